// Round 3
// baseline (608.416 us; speedup 1.0000x reference)
//
#include <hip/hip_runtime.h>
#include <hip/hip_bf16.h>
#include <math.h>

// q [8192,1024] f32, k [8192,1024] f32, v [8192,1024] f32
// scores = q@k^T; x = scores/||row|| * sqrt(8192); gated = gelu_exact(x); out = gated@v
//
// ws layout (~176 MiB):
//   [0,16M)    qb   bf16 8192x1024
//   [16M,32M)  kb   bf16 8192x1024
//   [32M,48M)  vbT  bf16 1024x8192
//   [48M,176M) scores/gated bf16 8192x8192 (in-place gelu)
//   [176M,+32K) sumsq->scale f32 [8192]
//
// R3: XOR-swizzled LDS staging for both GEMMs. global_load_lds forces
// dst=tid*16B, so the swizzle is applied on the SOURCE side: thread (sr,sg)
// stages k-group (sg ^ swz(sr)), swz(r)=(r&3)^((r>>2)&3). Readers use slot
// quad^swz(l16). This takes the quad's 16 lanes from 2 banks (8-way conflict)
// to 2 lanes/bank (free per m136).

#define MROWS 8192
#define DIN   1024
#define NBANK 8192
#define DOUT  1024

typedef float  f32x4  __attribute__((ext_vector_type(4)));
typedef __bf16 bf16x8 __attribute__((ext_vector_type(8)));

__device__ __forceinline__ float bf2f(unsigned short u) {
  union { unsigned int i; float f; } x; x.i = ((unsigned int)u) << 16; return x.f;
}
__device__ __forceinline__ unsigned short f2bf(float f) {
  union { float f; unsigned int i; } x; x.f = f;
  unsigned int u = x.i;
  unsigned int r = (u + 0x7fffu + ((u >> 16) & 1u)) >> 16;  // RNE
  return (unsigned short)r;
}
__device__ __forceinline__ int swz4(int r) { return (r & 3) ^ ((r >> 2) & 3); }

// ---------------- fp32 -> bf16 convert ----------------
__global__ void cvt_kernel(const float* __restrict__ src,
                           unsigned short* __restrict__ dst, int n) {
  int i = (blockIdx.x * 256 + threadIdx.x) * 4;
  if (i >= n) return;
  float4 vv = *(const float4*)(src + i);
  ushort4 o;
  o.x = f2bf(vv.x); o.y = f2bf(vv.y); o.z = f2bf(vv.z); o.w = f2bf(vv.w);
  *(ushort4*)(dst + i) = o;
}

// ---------------- transpose + convert: src[R][C] f32 -> dst[C][R] bf16 ----------------
__global__ void transpose_cvt_kernel(const float* __restrict__ src,
                                     unsigned short* __restrict__ dst,
                                     int R, int C) {
  __shared__ float tile[32][33];
  int c0 = blockIdx.x * 32, r0 = blockIdx.y * 32;
  for (int i = threadIdx.y; i < 32; i += 8)
    tile[i][threadIdx.x] = src[(size_t)(r0 + i) * C + c0 + threadIdx.x];
  __syncthreads();
  for (int i = threadIdx.y; i < 32; i += 8)
    dst[(size_t)(c0 + i) * R + r0 + threadIdx.x] = f2bf(tile[threadIdx.x][i]);
}

// ---------------- zero fill (float4 granularity) ----------------
__global__ void zero_f32_kernel(float* __restrict__ p, int n4) {
  int i = blockIdx.x * 256 + threadIdx.x;
  if (i < n4) ((float4*)p)[i] = make_float4(0.f, 0.f, 0.f, 0.f);
}

// ---------------- GEMM1: scores = qb @ kb^T (bf16 out) + row sumsq atomics ----------
__global__ __launch_bounds__(256, 2) void gemm1_kernel(
    const unsigned short* __restrict__ A, const unsigned short* __restrict__ B,
    unsigned short* __restrict__ C, float* __restrict__ sumsq) {
  __shared__ unsigned short As[128 * 32];
  __shared__ unsigned short Bs[128 * 32];
  const int K = DIN, ldc = NBANK;

  const int tid  = threadIdx.x;
  const int lane = tid & 63;
  const int wave = tid >> 6;
  const int wm   = (wave >> 1) * 64;
  const int wn   = (wave & 1) * 64;
  const int quad = lane >> 4;
  const int l16  = lane & 15;

  const size_t m0 = (size_t)blockIdx.y * 128;
  const size_t n0 = (size_t)blockIdx.x * 128;

  // swizzled staging: thread t = (srow, sg) loads k-group sg^swz(srow)
  const int srow = tid >> 2;
  const int sg   = tid & 3;
  const int scol = (sg ^ swz4(srow)) * 8;
  const unsigned short* Ag0 = A + (m0 + srow) * (size_t)K + scol;
  const unsigned short* Ag1 = A + (m0 + srow + 64) * (size_t)K + scol;
  const unsigned short* Bg0 = B + (n0 + srow) * (size_t)K + scol;
  const unsigned short* Bg1 = B + (n0 + srow + 64) * (size_t)K + scol;

  unsigned short* AsW0 = As + tid * 8;
  unsigned short* AsW1 = As + 64 * 32 + tid * 8;
  unsigned short* BsW0 = Bs + tid * 8;
  unsigned short* BsW1 = Bs + 64 * 32 + tid * 8;

  // swizzled read slot: quad ^ swz(l16) (row offsets wm,i*16 are ≡0 mod 16)
  const int rslot = (quad ^ swz4(l16)) * 8;
  const unsigned short* ArP = As + (wm + l16) * 32 + rslot;
  const unsigned short* BrP = Bs + (wn + l16) * 32 + rslot;

  f32x4 acc[4][4];
#pragma unroll
  for (int i = 0; i < 4; i++)
#pragma unroll
    for (int j = 0; j < 4; j++) {
      f32x4 z = {0.f, 0.f, 0.f, 0.f};
      acc[i][j] = z;
    }

  for (int k0 = 0; k0 < K; k0 += 32) {
    __builtin_amdgcn_global_load_lds(
        (const __attribute__((address_space(1))) unsigned int*)(Ag0 + k0),
        (__attribute__((address_space(3))) unsigned int*)AsW0, 16, 0, 0);
    __builtin_amdgcn_global_load_lds(
        (const __attribute__((address_space(1))) unsigned int*)(Ag1 + k0),
        (__attribute__((address_space(3))) unsigned int*)AsW1, 16, 0, 0);
    __builtin_amdgcn_global_load_lds(
        (const __attribute__((address_space(1))) unsigned int*)(Bg0 + k0),
        (__attribute__((address_space(3))) unsigned int*)BsW0, 16, 0, 0);
    __builtin_amdgcn_global_load_lds(
        (const __attribute__((address_space(1))) unsigned int*)(Bg1 + k0),
        (__attribute__((address_space(3))) unsigned int*)BsW1, 16, 0, 0);
    __syncthreads();

    bf16x8 af[4], bfr[4];
#pragma unroll
    for (int i = 0; i < 4; i++) af[i] = *(const bf16x8*)(ArP + i * 16 * 32);
#pragma unroll
    for (int j = 0; j < 4; j++) bfr[j] = *(const bf16x8*)(BrP + j * 16 * 32);
#pragma unroll
    for (int i = 0; i < 4; i++)
#pragma unroll
      for (int j = 0; j < 4; j++)
        acc[i][j] = __builtin_amdgcn_mfma_f32_16x16x32_bf16(af[i], bfr[j],
                                                            acc[i][j], 0, 0, 0);
    __syncthreads();
  }

  // Epilogue: store bf16 scores + per-row sum-of-squares (f32 acc) via atomics.
#pragma unroll
  for (int i = 0; i < 4; i++)
#pragma unroll
    for (int r = 0; r < 4; r++) {
      size_t row = m0 + wm + i * 16 + quad * 4 + r;
      float s = 0.f;
#pragma unroll
      for (int j = 0; j < 4; j++) {
        float val = acc[i][j][r];
        s += val * val;
        C[row * (size_t)ldc + n0 + wn + j * 16 + l16] = f2bf(val);
      }
      s += __shfl_xor(s, 1);
      s += __shfl_xor(s, 2);
      s += __shfl_xor(s, 4);
      s += __shfl_xor(s, 8);
      if (l16 == 0) atomicAdd(&sumsq[row], s);
    }
}

// ---------------- scale = sqrt(N / sumsq), in place ----------------
__global__ void finalize_scale_kernel(float* __restrict__ s) {
  int i = blockIdx.x * 256 + threadIdx.x;
  if (i < MROWS) s[i] = sqrtf((float)NBANK / s[i]);
}

// ---------------- in-place exact GELU(x * scale[row]) ----------------
__global__ void gelu_kernel(unsigned short* __restrict__ S,
                            const float* __restrict__ scale) {
  size_t idx = ((size_t)blockIdx.x * 256 + threadIdx.x) * 8;
  int row = (int)(idx >> 13);
  float sc = scale[row];
  uint4 vv = *(const uint4*)(S + idx);
  unsigned int w[4] = {vv.x, vv.y, vv.z, vv.w};
#pragma unroll
  for (int e = 0; e < 4; e++) {
    float x0 = bf2f((unsigned short)(w[e] & 0xffffu)) * sc;
    float x1 = bf2f((unsigned short)(w[e] >> 16)) * sc;
    float g0 = 0.5f * x0 * (1.0f + erff(x0 * 0.70710678118654752f));
    float g1 = 0.5f * x1 * (1.0f + erff(x1 * 0.70710678118654752f));
    w[e] = (unsigned int)f2bf(g0) | ((unsigned int)f2bf(g1) << 16);
  }
  uint4 o; o.x = w[0]; o.y = w[1]; o.z = w[2]; o.w = w[3];
  *(uint4*)(S + idx) = o;
}

// ---------------- GEMM2: out += gated @ vbT^T, 128x256 tile, split-K x2 --------------
__global__ __launch_bounds__(512, 4) void gemm2_kernel(
    const unsigned short* __restrict__ A,   // gated [8192][8192]
    const unsigned short* __restrict__ B,   // vbT   [1024][8192]
    float* __restrict__ C) {                // out   [8192][1024], pre-zeroed
  __shared__ unsigned short As[128 * 32];   //  8 KiB
  __shared__ unsigned short Bs[256 * 32];   // 16 KiB
  const int K = NBANK, ldc = DOUT;

  const int tid  = threadIdx.x;
  const int lane = tid & 63;
  const int wave = tid >> 6;          // 0..7
  const int wm   = (wave >> 2) * 64;  // 0,64
  const int wn   = (wave & 3) * 64;   // 0,64,128,192
  const int quad = lane >> 4;
  const int l16  = lane & 15;

  const size_t m0 = (size_t)blockIdx.y * 128;
  const size_t n0 = (size_t)blockIdx.x * 256;
  const int    ks = blockIdx.z * (K / 2);

  const int srow = tid >> 2;          // 0..127
  const int sg   = tid & 3;
  const int scol = (sg ^ swz4(srow)) * 8;
  const unsigned short* Ag  = A + (m0 + srow) * (size_t)K + scol + ks;
  const unsigned short* Bg0 = B + (n0 + srow) * (size_t)K + scol + ks;
  const unsigned short* Bg1 = B + (n0 + srow + 128) * (size_t)K + scol + ks;

  unsigned short* AsW  = As + tid * 8;
  unsigned short* BsW0 = Bs + tid * 8;
  unsigned short* BsW1 = Bs + 512 * 8 + tid * 8;

  const int rslot = (quad ^ swz4(l16)) * 8;
  const unsigned short* ArP = As + (wm + l16) * 32 + rslot;
  const unsigned short* BrP = Bs + (wn + l16) * 32 + rslot;

  f32x4 acc[4][4];
#pragma unroll
  for (int i = 0; i < 4; i++)
#pragma unroll
    for (int j = 0; j < 4; j++) {
      f32x4 z = {0.f, 0.f, 0.f, 0.f};
      acc[i][j] = z;
    }

  for (int k0 = 0; k0 < K / 2; k0 += 32) {
    __builtin_amdgcn_global_load_lds(
        (const __attribute__((address_space(1))) unsigned int*)(Ag + k0),
        (__attribute__((address_space(3))) unsigned int*)AsW, 16, 0, 0);
    __builtin_amdgcn_global_load_lds(
        (const __attribute__((address_space(1))) unsigned int*)(Bg0 + k0),
        (__attribute__((address_space(3))) unsigned int*)BsW0, 16, 0, 0);
    __builtin_amdgcn_global_load_lds(
        (const __attribute__((address_space(1))) unsigned int*)(Bg1 + k0),
        (__attribute__((address_space(3))) unsigned int*)BsW1, 16, 0, 0);
    __syncthreads();

    bf16x8 af[4], bfr[4];
#pragma unroll
    for (int i = 0; i < 4; i++) af[i] = *(const bf16x8*)(ArP + i * 16 * 32);
#pragma unroll
    for (int j = 0; j < 4; j++) bfr[j] = *(const bf16x8*)(BrP + j * 16 * 32);
#pragma unroll
    for (int i = 0; i < 4; i++)
#pragma unroll
      for (int j = 0; j < 4; j++)
        acc[i][j] = __builtin_amdgcn_mfma_f32_16x16x32_bf16(af[i], bfr[j],
                                                            acc[i][j], 0, 0, 0);
    __syncthreads();
  }

#pragma unroll
  for (int i = 0; i < 4; i++)
#pragma unroll
    for (int j = 0; j < 4; j++)
#pragma unroll
      for (int r = 0; r < 4; r++) {
        size_t row = m0 + wm + i * 16 + quad * 4 + r;
        size_t col = n0 + wn + j * 16 + l16;
        atomicAdd(&C[row * (size_t)ldc + col], acc[i][j][r]);
      }
}

extern "C" void kernel_launch(void* const* d_in, const int* in_sizes, int n_in,
                              void* d_out, int out_size, void* d_ws, size_t ws_size,
                              hipStream_t stream) {
  const float* q = (const float*)d_in[0];
  const float* k = (const float*)d_in[1];
  const float* v = (const float*)d_in[2];
  float* out = (float*)d_out;

  char* ws = (char*)d_ws;
  const size_t MB = 1024ull * 1024ull;
  unsigned short* qb     = (unsigned short*)(ws);
  unsigned short* kb     = (unsigned short*)(ws + 16 * MB);
  unsigned short* vbT    = (unsigned short*)(ws + 32 * MB);
  unsigned short* scores = (unsigned short*)(ws + 48 * MB);
  float*          scale  = (float*)(ws + 176 * MB);  // sumsq, then scale in place

  const int nqk = MROWS * DIN;

  zero_f32_kernel<<<(MROWS * DOUT / 4 + 255) / 256, 256, 0, stream>>>(out,
                                                                      MROWS * DOUT / 4);
  zero_f32_kernel<<<(MROWS / 4 + 255) / 256, 256, 0, stream>>>(scale, MROWS / 4);

  cvt_kernel<<<nqk / 1024, 256, 0, stream>>>(q, qb, nqk);
  cvt_kernel<<<nqk / 1024, 256, 0, stream>>>(k, kb, nqk);
  transpose_cvt_kernel<<<dim3(DOUT / 32, NBANK / 32), dim3(32, 8), 0, stream>>>(
      v, vbT, NBANK, DOUT);

  gemm1_kernel<<<dim3(NBANK / 128, MROWS / 128), 256, 0, stream>>>(qb, kb, scores,
                                                                   scale);

  finalize_scale_kernel<<<MROWS / 256, 256, 0, stream>>>(scale);

  gelu_kernel<<<(MROWS * (size_t)NBANK) / (256 * 8), 256, 0, stream>>>(scores, scale);

  gemm2_kernel<<<dim3(DOUT / 256, MROWS / 128, 2), 512, 0, stream>>>(scores, vbT, out);
}

// Round 4
// 581.086 us; speedup vs baseline: 1.0470x; 1.0470x over previous
//
#include <hip/hip_runtime.h>
#include <hip/hip_bf16.h>
#include <math.h>

// q [8192,1024] f32, k [8192,1024] f32, v [8192,1024] f32
// scores = q@k^T; x = scores/||row|| * sqrt(8192); gated = gelu_exact(x); out = gated@v
//
// ws layout (~176 MiB):
//   [0,16M)    qb   bf16 8192x1024
//   [16M,32M)  kb   bf16 8192x1024
//   [32M,48M)  vbT  bf16 1024x8192
//   [48M,176M) scores/gated bf16 8192x8192 (in-place gelu)
//   [176M,+32K) sumsq->scale f32 [8192]
//
// R4: swizzle reverted (R3 showed it broke global request merging: FETCH +22%,
// MfmaUtil -6pt; SQ_LDS_BANK_CONFLICT is saturated at 2^24 and carries no
// signal). New experiment: BK=64 on both GEMMs — halves the per-K-step
// __syncthreads/vmcnt(0) drains, the m97 structural stall.

#define MROWS 8192
#define DIN   1024
#define NBANK 8192
#define DOUT  1024

typedef float  f32x4  __attribute__((ext_vector_type(4)));
typedef __bf16 bf16x8 __attribute__((ext_vector_type(8)));

__device__ __forceinline__ float bf2f(unsigned short u) {
  union { unsigned int i; float f; } x; x.i = ((unsigned int)u) << 16; return x.f;
}
__device__ __forceinline__ unsigned short f2bf(float f) {
  union { float f; unsigned int i; } x; x.f = f;
  unsigned int u = x.i;
  unsigned int r = (u + 0x7fffu + ((u >> 16) & 1u)) >> 16;  // RNE
  return (unsigned short)r;
}

// ---------------- fp32 -> bf16 convert ----------------
__global__ void cvt_kernel(const float* __restrict__ src,
                           unsigned short* __restrict__ dst, int n) {
  int i = (blockIdx.x * 256 + threadIdx.x) * 4;
  if (i >= n) return;
  float4 vv = *(const float4*)(src + i);
  ushort4 o;
  o.x = f2bf(vv.x); o.y = f2bf(vv.y); o.z = f2bf(vv.z); o.w = f2bf(vv.w);
  *(ushort4*)(dst + i) = o;
}

// ---------------- transpose + convert: src[R][C] f32 -> dst[C][R] bf16 ----------------
__global__ void transpose_cvt_kernel(const float* __restrict__ src,
                                     unsigned short* __restrict__ dst,
                                     int R, int C) {
  __shared__ float tile[32][33];
  int c0 = blockIdx.x * 32, r0 = blockIdx.y * 32;
  for (int i = threadIdx.y; i < 32; i += 8)
    tile[i][threadIdx.x] = src[(size_t)(r0 + i) * C + c0 + threadIdx.x];
  __syncthreads();
  for (int i = threadIdx.y; i < 32; i += 8)
    dst[(size_t)(c0 + i) * R + r0 + threadIdx.x] = f2bf(tile[threadIdx.x][i]);
}

// ---------------- zero fill (float4 granularity) ----------------
__global__ void zero_f32_kernel(float* __restrict__ p, int n4) {
  int i = blockIdx.x * 256 + threadIdx.x;
  if (i < n4) ((float4*)p)[i] = make_float4(0.f, 0.f, 0.f, 0.f);
}

// ---------------- GEMM1: scores = qb @ kb^T (bf16 out) + row sumsq atomics ----------
// 128x128 tile, BK=64, 256 threads (4 waves, 2x2 of 64x64 wave tiles).
__global__ __launch_bounds__(256, 2) void gemm1_kernel(
    const unsigned short* __restrict__ A, const unsigned short* __restrict__ B,
    unsigned short* __restrict__ C, float* __restrict__ sumsq) {
  __shared__ unsigned short As[128 * 64];  // 16 KiB
  __shared__ unsigned short Bs[128 * 64];  // 16 KiB
  const int K = DIN, ldc = NBANK;

  const int tid  = threadIdx.x;
  const int lane = tid & 63;
  const int wave = tid >> 6;
  const int wm   = (wave >> 1) * 64;
  const int wn   = (wave & 1) * 64;
  const int quad = lane >> 4;
  const int l16  = lane & 15;

  const size_t m0 = (size_t)blockIdx.y * 128;
  const size_t n0 = (size_t)blockIdx.x * 128;

  // staging: granule g = i*256 + tid; row = g>>3 = i*32 + (tid>>3), col = (g&7)*8
  const int srow = tid >> 3;
  const int scol = (tid & 7) * 8;
  const unsigned short* Ag = A + (m0 + srow) * (size_t)K + scol;
  const unsigned short* Bg = B + (n0 + srow) * (size_t)K + scol;
  unsigned short* AsW = As + tid * 8;
  unsigned short* BsW = Bs + tid * 8;

  const unsigned short* ArP = As + (wm + l16) * 64 + quad * 8;
  const unsigned short* BrP = Bs + (wn + l16) * 64 + quad * 8;

  f32x4 acc[4][4];
#pragma unroll
  for (int i = 0; i < 4; i++)
#pragma unroll
    for (int j = 0; j < 4; j++) {
      f32x4 z = {0.f, 0.f, 0.f, 0.f};
      acc[i][j] = z;
    }

  for (int k0 = 0; k0 < K; k0 += 64) {
#pragma unroll
    for (int i = 0; i < 4; i++) {
      __builtin_amdgcn_global_load_lds(
          (const __attribute__((address_space(1))) unsigned int*)(Ag + (size_t)i * 32 * K + k0),
          (__attribute__((address_space(3))) unsigned int*)(AsW + i * 2048), 16, 0, 0);
      __builtin_amdgcn_global_load_lds(
          (const __attribute__((address_space(1))) unsigned int*)(Bg + (size_t)i * 32 * K + k0),
          (__attribute__((address_space(3))) unsigned int*)(BsW + i * 2048), 16, 0, 0);
    }
    __syncthreads();

#pragma unroll
    for (int kk = 0; kk < 2; kk++) {
      bf16x8 af[4], bfr[4];
#pragma unroll
      for (int i = 0; i < 4; i++) af[i] = *(const bf16x8*)(ArP + i * 16 * 64 + kk * 32);
#pragma unroll
      for (int j = 0; j < 4; j++) bfr[j] = *(const bf16x8*)(BrP + j * 16 * 64 + kk * 32);
#pragma unroll
      for (int i = 0; i < 4; i++)
#pragma unroll
        for (int j = 0; j < 4; j++)
          acc[i][j] = __builtin_amdgcn_mfma_f32_16x16x32_bf16(af[i], bfr[j],
                                                              acc[i][j], 0, 0, 0);
    }
    __syncthreads();
  }

  // Epilogue: store bf16 scores + per-row sum-of-squares (f32 acc) via atomics.
#pragma unroll
  for (int i = 0; i < 4; i++)
#pragma unroll
    for (int r = 0; r < 4; r++) {
      size_t row = m0 + wm + i * 16 + quad * 4 + r;
      float s = 0.f;
#pragma unroll
      for (int j = 0; j < 4; j++) {
        float val = acc[i][j][r];
        s += val * val;
        C[row * (size_t)ldc + n0 + wn + j * 16 + l16] = f2bf(val);
      }
      s += __shfl_xor(s, 1);
      s += __shfl_xor(s, 2);
      s += __shfl_xor(s, 4);
      s += __shfl_xor(s, 8);
      if (l16 == 0) atomicAdd(&sumsq[row], s);
    }
}

// ---------------- scale = sqrt(N / sumsq), in place ----------------
__global__ void finalize_scale_kernel(float* __restrict__ s) {
  int i = blockIdx.x * 256 + threadIdx.x;
  if (i < MROWS) s[i] = sqrtf((float)NBANK / s[i]);
}

// ---------------- in-place exact GELU(x * scale[row]) ----------------
__global__ void gelu_kernel(unsigned short* __restrict__ S,
                            const float* __restrict__ scale) {
  size_t idx = ((size_t)blockIdx.x * 256 + threadIdx.x) * 8;
  int row = (int)(idx >> 13);
  float sc = scale[row];
  uint4 vv = *(const uint4*)(S + idx);
  unsigned int w[4] = {vv.x, vv.y, vv.z, vv.w};
#pragma unroll
  for (int e = 0; e < 4; e++) {
    float x0 = bf2f((unsigned short)(w[e] & 0xffffu)) * sc;
    float x1 = bf2f((unsigned short)(w[e] >> 16)) * sc;
    float g0 = 0.5f * x0 * (1.0f + erff(x0 * 0.70710678118654752f));
    float g1 = 0.5f * x1 * (1.0f + erff(x1 * 0.70710678118654752f));
    w[e] = (unsigned int)f2bf(g0) | ((unsigned int)f2bf(g1) << 16);
  }
  uint4 o; o.x = w[0]; o.y = w[1]; o.z = w[2]; o.w = w[3];
  *(uint4*)(S + idx) = o;
}

// ---------------- GEMM2: out += gated @ vbT^T, 128x256 tile, BK=64, split-K x2 ------
// 512 threads = 8 waves in 2x4 grid of 64x64 wave tiles. f32 atomic accumulate.
__global__ __launch_bounds__(512, 2) void gemm2_kernel(
    const unsigned short* __restrict__ A,   // gated [8192][8192]
    const unsigned short* __restrict__ B,   // vbT   [1024][8192]
    float* __restrict__ C) {                // out   [8192][1024], pre-zeroed
  __shared__ unsigned short As[128 * 64];   // 16 KiB
  __shared__ unsigned short Bs[256 * 64];   // 32 KiB
  const int K = NBANK, ldc = DOUT;

  const int tid  = threadIdx.x;
  const int lane = tid & 63;
  const int wave = tid >> 6;          // 0..7
  const int wm   = (wave >> 2) * 64;  // 0,64
  const int wn   = (wave & 3) * 64;   // 0,64,128,192
  const int quad = lane >> 4;
  const int l16  = lane & 15;

  const size_t m0 = (size_t)blockIdx.y * 128;
  const size_t n0 = (size_t)blockIdx.x * 256;
  const int    ks = blockIdx.z * (K / 2);

  // staging: granule g = i*512 + tid; row = i*64 + (tid>>3), col = (tid&7)*8
  const int srow = tid >> 3;          // 0..63
  const int scol = (tid & 7) * 8;
  const unsigned short* Ag = A + (m0 + srow) * (size_t)K + scol + ks;
  const unsigned short* Bg = B + (n0 + srow) * (size_t)K + scol + ks;
  unsigned short* AsW = As + tid * 8;
  unsigned short* BsW = Bs + tid * 8;

  const unsigned short* ArP = As + (wm + l16) * 64 + quad * 8;
  const unsigned short* BrP = Bs + (wn + l16) * 64 + quad * 8;

  f32x4 acc[4][4];
#pragma unroll
  for (int i = 0; i < 4; i++)
#pragma unroll
    for (int j = 0; j < 4; j++) {
      f32x4 z = {0.f, 0.f, 0.f, 0.f};
      acc[i][j] = z;
    }

  for (int k0 = 0; k0 < K / 2; k0 += 64) {
#pragma unroll
    for (int i = 0; i < 2; i++)
      __builtin_amdgcn_global_load_lds(
          (const __attribute__((address_space(1))) unsigned int*)(Ag + (size_t)i * 64 * K + k0),
          (__attribute__((address_space(3))) unsigned int*)(AsW + i * 4096), 16, 0, 0);
#pragma unroll
    for (int i = 0; i < 4; i++)
      __builtin_amdgcn_global_load_lds(
          (const __attribute__((address_space(1))) unsigned int*)(Bg + (size_t)i * 64 * K + k0),
          (__attribute__((address_space(3))) unsigned int*)(BsW + i * 4096), 16, 0, 0);
    __syncthreads();

#pragma unroll
    for (int kk = 0; kk < 2; kk++) {
      bf16x8 af[4], bfr[4];
#pragma unroll
      for (int i = 0; i < 4; i++) af[i] = *(const bf16x8*)(ArP + i * 16 * 64 + kk * 32);
#pragma unroll
      for (int j = 0; j < 4; j++) bfr[j] = *(const bf16x8*)(BrP + j * 16 * 64 + kk * 32);
#pragma unroll
      for (int i = 0; i < 4; i++)
#pragma unroll
        for (int j = 0; j < 4; j++)
          acc[i][j] = __builtin_amdgcn_mfma_f32_16x16x32_bf16(af[i], bfr[j],
                                                              acc[i][j], 0, 0, 0);
    }
    __syncthreads();
  }

#pragma unroll
  for (int i = 0; i < 4; i++)
#pragma unroll
    for (int j = 0; j < 4; j++)
#pragma unroll
      for (int r = 0; r < 4; r++) {
        size_t row = m0 + wm + i * 16 + quad * 4 + r;
        size_t col = n0 + wn + j * 16 + l16;
        atomicAdd(&C[row * (size_t)ldc + col], acc[i][j][r]);
      }
}

extern "C" void kernel_launch(void* const* d_in, const int* in_sizes, int n_in,
                              void* d_out, int out_size, void* d_ws, size_t ws_size,
                              hipStream_t stream) {
  const float* q = (const float*)d_in[0];
  const float* k = (const float*)d_in[1];
  const float* v = (const float*)d_in[2];
  float* out = (float*)d_out;

  char* ws = (char*)d_ws;
  const size_t MB = 1024ull * 1024ull;
  unsigned short* qb     = (unsigned short*)(ws);
  unsigned short* kb     = (unsigned short*)(ws + 16 * MB);
  unsigned short* vbT    = (unsigned short*)(ws + 32 * MB);
  unsigned short* scores = (unsigned short*)(ws + 48 * MB);
  float*          scale  = (float*)(ws + 176 * MB);  // sumsq, then scale in place

  const int nqk = MROWS * DIN;

  zero_f32_kernel<<<(MROWS * DOUT / 4 + 255) / 256, 256, 0, stream>>>(out,
                                                                      MROWS * DOUT / 4);
  zero_f32_kernel<<<(MROWS / 4 + 255) / 256, 256, 0, stream>>>(scale, MROWS / 4);

  cvt_kernel<<<nqk / 1024, 256, 0, stream>>>(q, qb, nqk);
  cvt_kernel<<<nqk / 1024, 256, 0, stream>>>(k, kb, nqk);
  transpose_cvt_kernel<<<dim3(DOUT / 32, NBANK / 32), dim3(32, 8), 0, stream>>>(
      v, vbT, NBANK, DOUT);

  gemm1_kernel<<<dim3(NBANK / 128, MROWS / 128), 256, 0, stream>>>(qb, kb, scores,
                                                                   scale);

  finalize_scale_kernel<<<MROWS / 256, 256, 0, stream>>>(scale);

  gelu_kernel<<<(MROWS * (size_t)NBANK) / (256 * 8), 256, 0, stream>>>(scores, scale);

  gemm2_kernel<<<dim3(DOUT / 256, MROWS / 128, 2), 512, 0, stream>>>(scores, vbT, out);
}